// Round 2
// 1896.917 us; speedup vs baseline: 1.0112x; 1.0112x over previous
//
#include <hip/hip_runtime.h>

#define B_   128
#define T_   128
#define DIN  64
#define H_   1024
#define NBLK 256
#define NTHR 1024

typedef _Float16 f16;
typedef _Float16 half8 __attribute__((ext_vector_type(8)));
typedef float float4v __attribute__((ext_vector_type(4)));
typedef unsigned uint2v __attribute__((ext_vector_type(2)));
typedef unsigned uint4v __attribute__((ext_vector_type(4)));

// h layout (block-major, exclusive line ownership):
//   h(m, col) at  buf[(col>>2)*512 + m*4 + (col&3)]   (f16 elements)
// Block b writes its 4 columns as ONE contiguous 1KB region [b*512 .. b*512+512).

// LDS layout (16-wave K-split: partial gate buffers A/B per layer):
//  W1s  : f16[34][512]                                  34816 B
//  W2s  : f16[64][512]                                  65536 B
//  Sg1A : float[128][17]   (waves 0-7,  K-half 0)        8704 B
//  Sg1B : float[128][17]   (waves 8-15, K-half 1)        8704 B
//  Sg2A : float[128][17]                                 8704 B
//  Sg2B : float[128][17]                                 8704 B
//  c1,c2: float[512] each                                4096 B
//  bs1,bs2: float[16] each                                128 B   total 139392
#define OFF_W2    34816
#define OFF_SG1A  100352
#define OFF_SG1B  109056
#define OFF_SG2A  117760
#define OFF_SG2B  126464
#define OFF_C1    135168
#define OFF_C2    137216
#define OFF_B1    139264
#define OFF_B2    139328
#define SMEM_BYTES 139392

// Barrier state S (unsigned[2048], 8 KB), one 128-B line per hot word:
//  S[x*32]         : per-XCD ticket
//  S[512]          : central XCD counter
//  S[544]          : release word            (polled by <=8 XCD leaders)
//  S[576 + x*32]   : per-XCD go flag         (polled by <=31 blocks)
//  S[1088 + x*32]  : per-XCD inv-done flag   (polled by 1 leader)
//  S[1600 + x]     : per-XCD block count     (preamble only)

struct Params {
  const float *x, *Wih1, *Whh1, *bih1, *bhh1, *Wih2, *Whh2, *bih2, *bhh2,
              *Wlin, *blin, *Whio, *bhio;
  const int* fut;
  float* out;
  f16 *x16, *h1a, *h1b, *h2a, *h2b, *ob;
  unsigned *arrive, *rel;
  unsigned *S;
};

__device__ __forceinline__ float sigm(float v) { return 1.f / (1.f + __expf(-v)); }
__device__ __forceinline__ float tanh_(float v) { return 2.f / (1.f + __expf(-2.f * v)) - 1.f; }

__device__ __forceinline__ unsigned get_xcc() {
  unsigned x;
  asm volatile("s_getreg_b32 %0, hwreg(HW_REG_XCC_ID)" : "=s"(x));
  return x & 15u;
}

// ---- slow barrier (preamble only) -----------------------------------------
__device__ __forceinline__ void grid_sync(unsigned* arrive, unsigned* rel, unsigned ph) {
  __syncthreads();
  const int tid = threadIdx.x, bid = blockIdx.x;
  if (bid == 0) {
    if (tid > 0 && tid < NBLK) {
      while (__hip_atomic_load(&arrive[tid], __ATOMIC_RELAXED, __HIP_MEMORY_SCOPE_AGENT) != ph)
        __builtin_amdgcn_s_sleep(8);
    }
    __syncthreads();
    if (tid == 0)
      __hip_atomic_store(rel, ph, __ATOMIC_RELEASE, __HIP_MEMORY_SCOPE_AGENT);
  } else {
    if (tid == 0) {
      __hip_atomic_store(&arrive[bid], ph, __ATOMIC_RELEASE, __HIP_MEMORY_SCOPE_AGENT);
      while (__hip_atomic_load(rel, __ATOMIC_RELAXED, __HIP_MEMORY_SCOPE_AGENT) != ph)
        __builtin_amdgcn_s_sleep(8);
    }
  }
  __syncthreads();
  __builtin_amdgcn_fence(__ATOMIC_ACQUIRE, "agent");
}

// ---- fast barrier v4 (R8-proven): L2-inv hoisted to arrive-time -----------
__device__ __forceinline__ void fast_sync(unsigned* S, unsigned x, unsigned xtotal,
                                          unsigned nxcd, unsigned ph) {
  __syncthreads();
  if (threadIdx.x == 0) {
    unsigned t = __hip_atomic_fetch_add(&S[x * 32], 1u, __ATOMIC_RELAXED, __HIP_MEMORY_SCOPE_AGENT);
    bool leader = (t % xtotal == 0u);
    if ((t + 1u) % xtotal == 0u) {
      unsigned c = __hip_atomic_fetch_add(&S[512], 1u, __ATOMIC_RELAXED, __HIP_MEMORY_SCOPE_AGENT);
      if ((c + 1u) % nxcd == 0u)
        __hip_atomic_store(&S[544], ph, __ATOMIC_RELAXED, __HIP_MEMORY_SCOPE_AGENT);
      asm volatile("buffer_inv sc0 sc1\n\ts_waitcnt vmcnt(0)" ::: "memory");
      __hip_atomic_store(&S[1088 + x * 32], ph, __ATOMIC_RELAXED, __HIP_MEMORY_SCOPE_AGENT);
    }
    if (leader) {
      while (__hip_atomic_load(&S[544], __ATOMIC_RELAXED, __HIP_MEMORY_SCOPE_AGENT) != ph)
        __builtin_amdgcn_s_sleep(1);
      while (__hip_atomic_load(&S[1088 + x * 32], __ATOMIC_RELAXED, __HIP_MEMORY_SCOPE_AGENT) != ph)
        __builtin_amdgcn_s_sleep(1);
      __hip_atomic_store(&S[576 + x * 32], ph, __ATOMIC_RELAXED, __HIP_MEMORY_SCOPE_AGENT);
      asm volatile("buffer_inv sc0\n\ts_waitcnt vmcnt(0)" ::: "memory");
    } else {
      while (__hip_atomic_load(&S[576 + x * 32], __ATOMIC_RELAXED, __HIP_MEMORY_SCOPE_AGENT) != ph)
        __builtin_amdgcn_s_sleep(2);
      asm volatile("buffer_inv sc0\n\ts_waitcnt vmcnt(0)" ::: "memory");
    }
  }
  __syncthreads();
}

__global__ void __launch_bounds__(NTHR, 4) lstm_k(Params p) {
  extern __shared__ char smem[];
  f16*   W1s  = (f16*)(smem);
  f16*   W2s  = (f16*)(smem + OFF_W2);
  float* Sg1A = (float*)(smem + OFF_SG1A);
  float* Sg1B = (float*)(smem + OFF_SG1B);
  float* Sg2A = (float*)(smem + OFF_SG2A);
  float* Sg2B = (float*)(smem + OFF_SG2B);
  float* c1   = (float*)(smem + OFF_C1);
  float* c2   = (float*)(smem + OFF_C2);
  float* bs1  = (float*)(smem + OFF_B1);
  float* bs2  = (float*)(smem + OFF_B2);

  const int tid = threadIdx.x, bid = blockIdx.x;
  const int hb  = bid * 4;
  const int fut = p.fut[0];
  const unsigned xcc = get_xcc();
  unsigned* S = p.S;

  if (bid == 0) {
    for (int i = tid; i < 2048; i += NTHR)
      __hip_atomic_store(&S[i], 0u, __ATOMIC_RELAXED, __HIP_MEMORY_SCOPE_AGENT);
  }

  // ---------------- preamble ------------------------------------------------
  for (int idx = tid; idx < 34 * 512; idx += NTHR) {
    int c = idx >> 9, r = idx & 511;
    int q = r >> 7, colw = (r >> 3) & 15, j = r & 7;
    int k = c * 32 + q * 8 + j;
    int row = (colw >> 2) * H_ + hb + (colw & 3);
    float v = (k < H_) ? p.Whh1[row * H_ + k] : p.Wih1[row * DIN + (k - H_)];
    W1s[idx] = (f16)v;
  }
  for (int idx = tid; idx < 64 * 512; idx += NTHR) {
    int c = idx >> 9, r = idx & 511;
    int q = r >> 7, colw = (r >> 3) & 15, j = r & 7;
    int k = c * 32 + q * 8 + j;
    int row = (colw >> 2) * H_ + hb + (colw & 3);
    float v = (k < H_) ? p.Wih2[row * H_ + k] : p.Whh2[row * H_ + (k - H_)];
    W2s[idx] = (f16)v;
  }
  if (tid < 16) {
    int row = (tid >> 2) * H_ + hb + (tid & 3);
    bs1[tid] = p.bih1[row] + p.bhh1[row];
    bs2[tid] = p.bih2[row] + p.bhh2[row];
  }
  for (int i = tid; i < 512; i += NTHR) { c1[i] = 0.f; c2[i] = 0.f; }
  for (int i = bid * NTHR + tid; i < B_ * T_ * DIN; i += NBLK * NTHR)
    p.x16[i] = (f16)p.x[i];
  for (int i = bid * NTHR + tid; i < B_ * H_; i += NBLK * NTHR) {
    p.h1a[i] = (f16)0.f; p.h1b[i] = (f16)0.f;
    p.h2a[i] = (f16)0.f; p.h2b[i] = (f16)0.f;
  }

  unsigned ph = 1;
  grid_sync(p.arrive, p.rel, ph);
  if (tid == 0)
    __hip_atomic_fetch_add(&S[1600 + xcc], 1u, __ATOMIC_RELAXED, __HIP_MEMORY_SCOPE_AGENT);
  ++ph;
  grid_sync(p.arrive, p.rel, ph);

  unsigned xtotal = __hip_atomic_load(&S[1600 + xcc], __ATOMIC_RELAXED, __HIP_MEMORY_SCOPE_AGENT);
  unsigned nxcd = 0;
  for (int i = 0; i < 16; ++i)
    nxcd += (__hip_atomic_load(&S[1600 + i], __ATOMIC_RELAXED, __HIP_MEMORY_SCOPE_AGENT) != 0u);

  auto gsync = [&]() { ++ph; fast_sync(S, xcc, xtotal, nxcd, ph); };

  // ---------- wave geometry: 16 waves = 8 m-tiles x 2 K-halves -------------
  const int lane = tid & 63, wq = tid >> 6;
  const int g  = wq >> 3;        // K-half group (0: j 0..15, 1: j 16..31)
  const int wv = wq & 7;         // m-tile
  const int col = lane & 15, quad = lane >> 4;
  const int m0 = wv * 16 + col;
  const int ko = quad * 8;
  const int jb = g * 16;
  // Bias carried ONLY by K-half 0 (partials are summed in lstm_pw).
  const float b1v = g ? 0.f : bs1[col];
  const float b2v = g ? 0.f : bs2[col];
  const f16* W1f = W1s + lane * 8;
  const f16* W2f = W2s + lane * 8;
  float* S1w = g ? Sg1B : Sg1A;
  float* S2w = g ? Sg2B : Sg2A;
  // block-major h read base: window j pieces at hX + j*4096 + hoff and +512
  const int hoff = quad * 1024 + m0 * 4;

  f16 *h1c = p.h1a, *h1n = p.h1b, *h2c = p.h2a, *h2n = p.h2b;

  auto lstm_pw = [&](const float* SgA, const float* SgB, float* cst, f16* hn) {
    int mm = tid >> 2, cc = tid & 3;
    int i0 = mm * 17 + cc;
    float gi = SgA[i0]      + SgB[i0];
    float gf = SgA[i0 + 4]  + SgB[i0 + 4];
    float gg = SgA[i0 + 8]  + SgB[i0 + 8];
    float go = SgA[i0 + 12] + SgB[i0 + 12];
    float cn = sigm(gf) * cst[tid] + sigm(gi) * tanh_(gg);
    cst[tid] = cn;
    f16 hv = (f16)(sigm(go) * tanh_(cn));
    int v = (int)__builtin_bit_cast(unsigned short, hv);
    int base = lane & ~3;
    int v0 = __shfl(v, base, 64),     v1 = __shfl(v, base + 1, 64);
    int v2 = __shfl(v, base + 2, 64), v3 = __shfl(v, base + 3, 64);
    if (cc == 0) {
      unsigned long long pk = (unsigned long long)(unsigned short)v0
        | ((unsigned long long)(unsigned short)v1 << 16)
        | ((unsigned long long)(unsigned short)v2 << 32)
        | ((unsigned long long)(unsigned short)v3 << 48);
      __hip_atomic_store((unsigned long long*)(hn + bid * 512 + mm * 4), pk,
                         __ATOMIC_RELAXED, __HIP_MEMORY_SCOPE_AGENT);
    }
  };

  auto ldwin = [&](const f16* hX, int j) -> half8 {
    const uint2v* q0 = (const uint2v*)(hX + j * 4096 + hoff);
    const uint2v* q1 = (const uint2v*)(hX + j * 4096 + hoff + 512);
    uint2v u0 = *q0, u1 = *q1;
    uint4v u = {u0[0], u0[1], u1[0], u1[1]};
    return __builtin_bit_cast(half8, u);
  };

  // fused phase: gates1(t+1) [l1] and gates2(t) [l2], both keyed on h1c.
  // K-split: group g covers windows jb..jb+15 (and x window 32+g for l1).
  auto phase = [&](bool l1, bool l2, const f16* xp, int xstr) {
    float4v a1 = {b1v, b1v, b1v, b1v};
    float4v a2 = {b2v, b2v, b2v, b2v};

    if (l1) {   // x part (row-major, read-only, cached) — one window per group
      half8 ax = *(const half8*)(xp + m0 * xstr + g * 32 + ko);
      a1 = __builtin_amdgcn_mfma_f32_16x16x32_f16(ax, *(const half8*)(W1f + (32 + g) * 512), a1, 0, 0, 0);
    }
    if (l1 && l2) {
      #pragma unroll
      for (int i = 0; i < 16; ++i) {
        int j = jb + i;
        half8 w1 = ldwin(h1c, j);
        half8 w2 = ldwin(h2c, j);
        a1 = __builtin_amdgcn_mfma_f32_16x16x32_f16(w1, *(const half8*)(W1f + j * 512), a1, 0, 0, 0);
        a2 = __builtin_amdgcn_mfma_f32_16x16x32_f16(w1, *(const half8*)(W2f + j * 512), a2, 0, 0, 0);
        a2 = __builtin_amdgcn_mfma_f32_16x16x32_f16(w2, *(const half8*)(W2f + (32 + j) * 512), a2, 0, 0, 0);
      }
    } else if (l1) {
      #pragma unroll
      for (int i = 0; i < 16; ++i) {
        int j = jb + i;
        half8 w1 = ldwin(h1c, j);
        a1 = __builtin_amdgcn_mfma_f32_16x16x32_f16(w1, *(const half8*)(W1f + j * 512), a1, 0, 0, 0);
      }
    } else if (l2) {
      #pragma unroll
      for (int i = 0; i < 16; ++i) {
        int j = jb + i;
        half8 w1 = ldwin(h1c, j);
        half8 w2 = ldwin(h2c, j);
        a2 = __builtin_amdgcn_mfma_f32_16x16x32_f16(w1, *(const half8*)(W2f + j * 512), a2, 0, 0, 0);
        a2 = __builtin_amdgcn_mfma_f32_16x16x32_f16(w2, *(const half8*)(W2f + (32 + j) * 512), a2, 0, 0, 0);
      }
    }

    // ---- merged epilogue: partial-gate staging + pointwise ----
    __syncthreads();
    if (l1) {
      #pragma unroll
      for (int r = 0; r < 4; ++r)
        S1w[(wv * 16 + quad * 4 + r) * 17 + col] = a1[r];
    }
    if (l2) {
      #pragma unroll
      for (int r = 0; r < 4; ++r)
        S2w[(wv * 16 + quad * 4 + r) * 17 + col] = a2[r];
    }
    __syncthreads();
    if (tid < 512) {
      if (l1) lstm_pw(Sg1A, Sg1B, c1, h1n);
      if (l2) lstm_pw(Sg2A, Sg2B, c2, h2n);
    }
  };

  // small projection: out[m][j] = h2 . W[j] + b[j]  (block-major h2 reads)
  auto out_phase = [&](const float* W, const float* bv, bool wout) {
    if (tid >= 512) return;
    int j = bid & 63, mgp = bid >> 6;
    int rid = tid >> 4, ks = tid & 15;
    int mrow = mgp * 32 + rid;
    const float* wr = W + j * H_ + ks * 64;
    float s = 0.f;
    #pragma unroll
    for (int q = 0; q < 16; ++q) {
      const uint2v* hp = (const uint2v*)(h2c + (ks * 16 + q) * 512 + mrow * 4);
      uint2v u = *hp;
      half8 hv4;
      { uint4v t = {u[0], u[1], 0u, 0u}; hv4 = __builtin_bit_cast(half8, t); }
      s += (float)hv4[0] * wr[q * 4 + 0] + (float)hv4[1] * wr[q * 4 + 1]
         + (float)hv4[2] * wr[q * 4 + 2] + (float)hv4[3] * wr[q * 4 + 3];
    }
    s += __shfl_down(s, 8, 16);
    s += __shfl_down(s, 4, 16);
    s += __shfl_down(s, 2, 16);
    s += __shfl_down(s, 1, 16);
    if (ks == 0) {
      float v = s + bv[j];
      f16 hv = (f16)v;
      __hip_atomic_store((unsigned short*)&p.ob[mrow * 64 + j],
                         __builtin_bit_cast(unsigned short, hv),
                         __ATOMIC_RELAXED, __HIP_MEMORY_SCOPE_AGENT);
      if (wout) p.out[mrow * 64 + j] = v;
    }
  };

  // ---------------- time loop: 129 fused phases ----------------------------
  for (int t = -1; t < T_; ++t) {
    bool l1 = (t + 1 < T_), l2 = (t >= 0);
    phase(l1, l2, p.x16 + (t + 1) * DIN, T_ * DIN);
    gsync();
    if (l1) { f16* tm = h1c; h1c = h1n; h1n = tm; }
    if (l2) { f16* tm = h2c; h2c = h2n; h2n = tm; }
  }
  out_phase(p.Wlin, p.blin, fut == 0);
  gsync();
  for (int f = 0; f < fut; ++f) {
    phase(true, false, p.ob, 64);
    gsync();
    { f16* tm = h1c; h1c = h1n; h1n = tm; }
    phase(false, true, p.ob, 64);
    gsync();
    { f16* tm = h2c; h2c = h2n; h2n = tm; }
    out_phase(p.Whio, p.bhio, f == fut - 1);
    gsync();
  }
}

extern "C" void kernel_launch(void* const* d_in, const int* in_sizes, int n_in,
                              void* d_out, int out_size, void* d_ws, size_t ws_size,
                              hipStream_t stream) {
  char* w = (char*)d_ws;
  auto carve = [&](size_t n) { char* r = w; w += (n + 255) & ~(size_t)255; return r; };

  Params p;
  p.x    = (const float*)d_in[0];
  p.Wih1 = (const float*)d_in[1];
  p.Whh1 = (const float*)d_in[2];
  p.bih1 = (const float*)d_in[3];
  p.bhh1 = (const float*)d_in[4];
  p.Wih2 = (const float*)d_in[5];
  p.Whh2 = (const float*)d_in[6];
  p.bih2 = (const float*)d_in[7];
  p.bhh2 = (const float*)d_in[8];
  p.Wlin = (const float*)d_in[9];
  p.blin = (const float*)d_in[10];
  p.Whio = (const float*)d_in[11];
  p.bhio = (const float*)d_in[12];
  p.fut  = (const int*)d_in[13];
  p.out  = (float*)d_out;

  p.x16 = (f16*)carve((size_t)B_ * T_ * DIN * 2);
  p.h1a = (f16*)carve((size_t)B_ * H_ * 2);
  p.h1b = (f16*)carve((size_t)B_ * H_ * 2);
  p.h2a = (f16*)carve((size_t)B_ * H_ * 2);
  p.h2b = (f16*)carve((size_t)B_ * H_ * 2);
  p.ob  = (f16*)carve((size_t)B_ * 64 * 2);
  p.arrive = (unsigned*)carve(NBLK * sizeof(unsigned));
  p.rel    = (unsigned*)carve(256);
  p.S      = (unsigned*)carve(2048 * sizeof(unsigned));

  (void)hipFuncSetAttribute((const void*)lstm_k,
                            hipFuncAttributeMaxDynamicSharedMemorySize, SMEM_BYTES);
  void* args[] = { &p };
  (void)hipLaunchCooperativeKernel((void*)lstm_k, dim3(NBLK), dim3(NTHR),
                                   args, SMEM_BYTES, stream);
}